// Round 7
// baseline (28231.961 us; speedup 1.0000x reference)
//
#include <hip/hip_runtime.h>

#define SLOPE 0.01f
#define BP 132   // padded f32 row stride (528B, 16B-aligned, breaks bank conflicts)

__device__ __forceinline__ int lower_bound(const int* __restrict__ a, int n, int v) {
    int lo = 0, hi = n;
    while (lo < hi) { int mid = (lo + hi) >> 1; if (a[mid] < v) lo = mid + 1; else hi = mid; }
    return lo;
}

__device__ __forceinline__ float dot4(float4 a, float4 b) {
    return a.x * b.x + a.y * b.y + a.z * b.z + a.w * b.w;
}

// ---------------------------------------------------------------------------
// DIAGNOSTIC round: pure-VALU, pure-f32 fused kernel. Block c = crystal c's
// segment of the sorted index; 4 waves = 4 heads; 16-node tiles; online
// softmax; no MFMA, no bf16, no workspace. Mirrors the reference exactly:
//   m    = leaky(fea@Wm1[h]^T + bm1)@Wm2[h]^T + bm2
//   l    = leaky([fea,cry[c]]@Wa1[h]^T + ba1) . Wa2[h] + ba2
//   out[c] = sum_n softmax_seg(l)_n * m_n
// ---------------------------------------------------------------------------
__global__ __launch_bounds__(256) void fused_valu(
    const float* __restrict__ fea, const float* __restrict__ cry,
    const float* __restrict__ Wm1, const float* __restrict__ bm1,
    const float* __restrict__ Wm2, const float* __restrict__ bm2,
    const float* __restrict__ Wa1, const float* __restrict__ ba1,
    const float* __restrict__ Wa2, const float* __restrict__ ba2,
    const int* __restrict__ index, int N, float* __restrict__ out)
{
    __shared__ __align__(16) float feaS[16][BP];
    __shared__ __align__(16) float cryS[128];
    __shared__ __align__(16) float buf[4][16][BP];
    __shared__ int sb[2];

    const int c = blockIdx.x, t = threadIdx.x;
    const int lane = t & 63, h = t >> 6;

    if (t == 0)  sb[0] = lower_bound(index, N, c);
    if (t == 64) sb[1] = lower_bound(index, N, c + 1);
    if (t < 128) cryS[t] = cry[(size_t)c * 128 + t];
    __syncthreads();
    const int start = sb[0], end = sb[1];

    if (start >= end) {                 // empty segment -> zeros (block-uniform)
        out[(size_t)c * 512 + t * 2]     = 0.f;
        out[(size_t)c * 512 + t * 2 + 1] = 0.f;
        return;
    }

    const float* wm1 = Wm1 + (size_t)h * 16384;   // [128][128] row-major [o][i]
    const float* wm2 = Wm2 + (size_t)h * 16384;
    const float* wa1 = Wa1 + (size_t)h * 32768;   // [128][256]
    const float* wa2 = Wa2 + (size_t)h * 128;
    const float bb_a2 = ba2[h];
    const int o1 = lane, o2 = lane + 64;
    const float bm1_1 = bm1[h * 128 + o1], bm1_2 = bm1[h * 128 + o2];
    const float bm2_1 = bm2[h * 128 + o1], bm2_2 = bm2[h * 128 + o2];
    const float ba1_1 = ba1[h * 128 + o1], ba1_2 = ba1[h * 128 + o2];

    float m_run = -1e30f, d_run = 0.f, sx = 0.f, sy = 0.f;

    for (int tb = start; tb < end; tb += 16) {
        int nv = end - tb; if (nv > 16) nv = 16;

        // ---- stage fea tile (zero-pad invalid rows) ----
        {
            int row = t >> 4, i0 = (t & 15) * 8;
            float4 v0 = {0.f, 0.f, 0.f, 0.f}, v1 = {0.f, 0.f, 0.f, 0.f};
            if (row < nv) {
                v0 = *(const float4*)(fea + (size_t)(tb + row) * 128 + i0);
                v1 = *(const float4*)(fea + (size_t)(tb + row) * 128 + i0 + 4);
            }
            *(float4*)&feaS[row][i0]     = v0;
            *(float4*)&feaS[row][i0 + 4] = v1;
        }
        __syncthreads();

        // ---- GEMM3: hA = leaky([fea|cry_c] @ Wa1^T + ba1) -> buf[h] ----
        for (int r = 0; r < 16; r++) {
            float s1 = ba1_1, s2 = ba1_2;
            for (int i = 0; i < 128; i += 4) {
                float4 x  = *(float4*)&feaS[r][i];
                s1 += dot4(x, *(const float4*)(wa1 + (size_t)o1 * 256 + i));
                s2 += dot4(x, *(const float4*)(wa1 + (size_t)o2 * 256 + i));
            }
            for (int i = 0; i < 128; i += 4) {
                float4 x  = *(float4*)&cryS[i];
                s1 += dot4(x, *(const float4*)(wa1 + (size_t)o1 * 256 + 128 + i));
                s2 += dot4(x, *(const float4*)(wa1 + (size_t)o2 * 256 + 128 + i));
            }
            buf[h][r][o1] = s1 >= 0.f ? s1 : SLOPE * s1;
            buf[h][r][o2] = s2 >= 0.f ? s2 : SLOPE * s2;
        }
        __syncthreads();

        // ---- logits: l[node] = hA[node,:] . Wa2 + ba2 (4 lanes per node) ----
        float l;
        {
            int nd = lane >> 2, p = lane & 3;
            float s = 0.f;
            for (int i = p * 32; i < p * 32 + 32; i += 4)
                s += dot4(*(float4*)&buf[h][nd][i], *(const float4*)(wa2 + i));
            s += __shfl_xor(s, 1);
            s += __shfl_xor(s, 2);
            l = s + bb_a2;
        }
        float l_all[16];
#pragma unroll
        for (int r = 0; r < 16; r++) l_all[r] = __shfl(l, r * 4);

        // ---- online softmax state update (wave-uniform) ----
        float tmax = -1e30f;
        for (int r = 0; r < nv; r++) tmax = fmaxf(tmax, l_all[r]);
        float m_new = fmaxf(m_run, tmax);
        float scf = __expf(m_run - m_new);
        sx *= scf; sy *= scf; d_run *= scf; m_run = m_new;
        __syncthreads();

        // ---- GEMM1: H1 = leaky(fea @ Wm1^T + bm1) -> buf[h] ----
        for (int r = 0; r < 16; r++) {
            float s1 = bm1_1, s2 = bm1_2;
            for (int i = 0; i < 128; i += 4) {
                float4 x = *(float4*)&feaS[r][i];
                s1 += dot4(x, *(const float4*)(wm1 + (size_t)o1 * 128 + i));
                s2 += dot4(x, *(const float4*)(wm1 + (size_t)o2 * 128 + i));
            }
            buf[h][r][o1] = s1 >= 0.f ? s1 : SLOPE * s1;
            buf[h][r][o2] = s2 >= 0.f ? s2 : SLOPE * s2;
        }
        __syncthreads();

        // ---- GEMM2 + weighted accumulation (m never stored) ----
        for (int r = 0; r < nv; r++) {
            float s1 = bm2_1, s2 = bm2_2;
            for (int i = 0; i < 128; i += 4) {
                float4 x = *(float4*)&buf[h][r][i];
                s1 += dot4(x, *(const float4*)(wm2 + (size_t)o1 * 128 + i));
                s2 += dot4(x, *(const float4*)(wm2 + (size_t)o2 * 128 + i));
            }
            float w = __expf(l_all[r] - m_run);
            d_run += w;
            sx += w * s1;
            sy += w * s2;
        }
        __syncthreads();
    }

    float inv = 1.f / (d_run + 1e-16f);
    out[(size_t)c * 512 + h * 128 + o1] = sx * inv;
    out[(size_t)c * 512 + h * 128 + o2] = sy * inv;
}

// ---------------------------------------------------------------------------
extern "C" void kernel_launch(void* const* d_in, const int* in_sizes, int n_in,
                              void* d_out, int out_size, void* d_ws, size_t ws_size,
                              hipStream_t stream)
{
    const float* fea = (const float*)d_in[0];
    const float* cry = (const float*)d_in[1];
    const float* Wm1 = (const float*)d_in[2];
    const float* bm1 = (const float*)d_in[3];
    const float* Wm2 = (const float*)d_in[4];
    const float* bm2 = (const float*)d_in[5];
    const float* Wa1 = (const float*)d_in[6];
    const float* ba1 = (const float*)d_in[7];
    const float* Wa2 = (const float*)d_in[8];
    const float* ba2 = (const float*)d_in[9];
    const int* index = (const int*)d_in[10];

    const int N = in_sizes[0] / 128;      // 200000
    const int S = out_size / 512;         // 16384

    fused_valu<<<S, 256, 0, stream>>>(fea, cry, Wm1, bm1, Wm2, bm2,
                                      Wa1, ba1, Wa2, ba2, index, N,
                                      (float*)d_out);
}

// Round 8
// 2711.794 us; speedup vs baseline: 10.4108x; 10.4108x over previous
//
#include <hip/hip_runtime.h>

typedef __bf16 bf16x8 __attribute__((ext_vector_type(8)));
typedef float  f32x4  __attribute__((ext_vector_type(4)));

#define PS 136   // padded LDS row stride (bf16 elems)
#define MFMA(a, b, c) __builtin_amdgcn_mfma_f32_16x16x32_bf16((a), (b), (c), 0, 0, 0)

// bf16 weight pack offsets in d_ws (elements)
#define O_WM1 0
#define O_WM2 65536
#define O_WA1 131072
#define O_WA2 262144
#define W_ELEMS 262656          // * 2 bytes = 525312 B needed in ws

__device__ __forceinline__ bf16x8 cvt8(const float* pf) {
    float4 a = *(const float4*)pf, b = *(const float4*)(pf + 4);
    bf16x8 o;
    o[0] = (__bf16)a.x; o[1] = (__bf16)a.y; o[2] = (__bf16)a.z; o[3] = (__bf16)a.w;
    o[4] = (__bf16)b.x; o[5] = (__bf16)b.y; o[6] = (__bf16)b.z; o[7] = (__bf16)b.w;
    return o;
}

__device__ __forceinline__ int lower_bound(const int* __restrict__ a, int n, int v) {
    int lo = 0, hi = n;
    while (lo < hi) { int mid = (lo + hi) >> 1; if (a[mid] < v) lo = mid + 1; else hi = mid; }
    return lo;
}

// ---------------------------------------------------------------------------
// Prep: pack 4 f32 weight tensors into contiguous bf16 in ws (lossless: data
// is bf16-rounded f32).
// ---------------------------------------------------------------------------
__global__ __launch_bounds__(256) void prep_kernel(
    const float* __restrict__ Wm1, const float* __restrict__ Wm2,
    const float* __restrict__ Wa1, const float* __restrict__ Wa2,
    __bf16* __restrict__ wb)
{
    int i8 = blockIdx.x * 256 + threadIdx.x;
    if (i8 >= W_ELEMS / 8) return;
    int i = i8 * 8;
    const float* src; int s;
    if      (i < O_WM2) { src = Wm1; s = i; }
    else if (i < O_WA1) { src = Wm2; s = i - O_WM2; }
    else if (i < O_WA2) { src = Wa1; s = i - O_WA1; }
    else                { src = Wa2; s = i - O_WA2; }
    *(bf16x8*)(wb + i) = cvt8(src + s);
}

// ---------------------------------------------------------------------------
// Fused per-crystal kernel. Block c = crystal c's segment (index sorted).
// 4 waves = 4 heads; 16-node tiles; online softmax; f32 in/out.
// MFMA 16x16x32 bf16 (verified): A[m=lane&15][k=(lane>>4)*8+j];
// B-frag = W[n=lane&15][kc+(lane>>4)*8+j]; D: col=lane&15, row=(lane>>4)*4+reg.
// GEMM2 output never touches LDS: weighted accumulation in registers,
// cross-q reduction by shfl_xor at block end.
// WB=true: weight fragments from bf16 pack in ws; else cvt from f32 global.
// ---------------------------------------------------------------------------
template<bool WB>
__device__ __forceinline__ bf16x8 wfrag(const __bf16* wb, const float* wf, size_t idx) {
    if constexpr (WB) return *(const bf16x8*)(wb + idx);
    else              return cvt8(wf + idx);
}

template<bool WB>
__device__ __forceinline__ void fused_body(
    const float* __restrict__ fea, const float* __restrict__ cry,
    const float* __restrict__ Wm1, const float* __restrict__ bm1,
    const float* __restrict__ Wm2, const float* __restrict__ bm2,
    const float* __restrict__ Wa1, const float* __restrict__ ba1,
    const float* __restrict__ Wa2, const float* __restrict__ ba2,
    const __bf16* __restrict__ wb,
    const int* __restrict__ index, int N, float* __restrict__ out)
{
    __shared__ __align__(16) __bf16 feaT[16 * PS];
    __shared__ __align__(16) __bf16 hT[4][16 * PS];
    __shared__ int sb[2];

    const int c = blockIdx.x, t = threadIdx.x;
    const int lane = t & 63, h = t >> 6, ml = lane & 15, q = lane >> 4;

    if (t == 0)  sb[0] = lower_bound(index, N, c);
    if (t == 64) sb[1] = lower_bound(index, N, c + 1);
    __syncthreads();
    const int start = sb[0], end = sb[1];

    // cry fragment: all node rows share cry[c] (broadcast across m)
    bf16x8 afc[4];
#pragma unroll
    for (int k = 0; k < 4; k++) afc[k] = cvt8(cry + (size_t)c * 128 + k * 32 + q * 8);

    // hoisted per-lane biases (col = ot*16+ml of head h)
    float ba1v[8], bm1v[8], bb2[8];
#pragma unroll
    for (int ot = 0; ot < 8; ot++) {
        ba1v[ot] = ba1[h * 128 + ot * 16 + ml];
        bm1v[ot] = bm1[h * 128 + ot * 16 + ml];
        bb2[ot]  = bm2[h * 128 + ot * 16 + ml];
    }
    const float ba2v = ba2[h];
    const float* wa2 = Wa2 + (size_t)h * 128;

    float m_run = -1e30f, d_run = 0.f;
    float wacc[8] = {0.f, 0.f, 0.f, 0.f, 0.f, 0.f, 0.f, 0.f};

    for (int tb = start; tb < end; tb += 16) {
        int nv = end - tb; if (nv > 16) nv = 16;

        // ---- stage fea tile (f32 -> bf16, zero-pad invalid rows) ----
        {
            int row = t >> 4, i0 = (t & 15) * 8;
            bf16x8 v;
#pragma unroll
            for (int j = 0; j < 8; j++) v[j] = (__bf16)0.f;
            if (row < nv) v = cvt8(fea + (size_t)(tb + row) * 128 + i0);
            *(bf16x8*)&feaT[row * PS + i0] = v;
        }
        __syncthreads();

        bf16x8 af[4];
#pragma unroll
        for (int k = 0; k < 4; k++) af[k] = *(bf16x8*)&feaT[ml * PS + k * 32 + q * 8];

        // ---- GEMM3: hA = leaky([fea | cry_c] @ Wa1[h]^T + ba1) -> hT[h] ----
#pragma unroll
        for (int ot = 0; ot < 8; ot++) {
            size_t wrow = (size_t)h * 32768 + (size_t)(ot * 16 + ml) * 256;
            f32x4 acc = {0.f, 0.f, 0.f, 0.f};
#pragma unroll
            for (int k = 0; k < 4; k++)
                acc = MFMA(af[k],  wfrag<WB>(wb + O_WA1, Wa1, wrow + k * 32 + q * 8), acc);
#pragma unroll
            for (int k = 0; k < 4; k++)
                acc = MFMA(afc[k], wfrag<WB>(wb + O_WA1, Wa1, wrow + 128 + k * 32 + q * 8), acc);
#pragma unroll
            for (int r = 0; r < 4; r++) {
                float v = acc[r] + ba1v[ot]; v = v >= 0.f ? v : 0.01f * v;
                hT[h][(q * 4 + r) * PS + ot * 16 + ml] = (__bf16)v;
            }
        }

        // ---- logits: l[node] = hA[node,:] . Wa2[h] + ba2[h] (4 lanes/node) ----
        float l;
        {
            int nd = lane >> 2, p = lane & 3;
            float s = 0.f;
#pragma unroll
            for (int cc = 0; cc < 4; cc++) {
                bf16x8 hv = *(bf16x8*)&hT[h][nd * PS + p * 32 + cc * 8];
                const float* wv = wa2 + p * 32 + cc * 8;
#pragma unroll
                for (int j = 0; j < 8; j++) s += (float)hv[j] * wv[j];
            }
            s += __shfl_xor(s, 1);
            s += __shfl_xor(s, 2);
            l = s + ba2v;
        }
        float l_all[16];
#pragma unroll
        for (int r = 0; r < 16; r++) l_all[r] = __shfl(l, r * 4);

        // ---- online softmax update (wave-uniform) ----
        float tmax = -1e30f;
        for (int r = 0; r < nv; r++) tmax = fmaxf(tmax, l_all[r]);
        float m_new = fmaxf(m_run, tmax);
        float scf = __expf(m_run - m_new);
#pragma unroll
        for (int ot = 0; ot < 8; ot++) wacc[ot] *= scf;
        d_run *= scf; m_run = m_new;

        float w_all[16];
#pragma unroll
        for (int r = 0; r < 16; r++) {
            w_all[r] = (r < nv) ? __expf(l_all[r] - m_run) : 0.f;
            d_run += w_all[r];
        }

        // ---- GEMM1: H1 = leaky(fea @ Wm1[h]^T + bm1) -> hT[h] ----
#pragma unroll
        for (int ot = 0; ot < 8; ot++) {
            size_t wrow = (size_t)h * 16384 + (size_t)(ot * 16 + ml) * 128;
            f32x4 acc = {0.f, 0.f, 0.f, 0.f};
#pragma unroll
            for (int k = 0; k < 4; k++)
                acc = MFMA(af[k], wfrag<WB>(wb + O_WM1, Wm1, wrow + k * 32 + q * 8), acc);
#pragma unroll
            for (int r = 0; r < 4; r++) {
                float v = acc[r] + bm1v[ot]; v = v >= 0.f ? v : 0.01f * v;
                hT[h][(q * 4 + r) * PS + ot * 16 + ml] = (__bf16)v;
            }
        }

        // ---- GEMM2 + weighted accumulation in registers ----
        {
            bf16x8 a2[4];
#pragma unroll
            for (int k = 0; k < 4; k++) a2[k] = *(bf16x8*)&hT[h][ml * PS + k * 32 + q * 8];
#pragma unroll
            for (int ot = 0; ot < 8; ot++) {
                size_t wrow = (size_t)h * 16384 + (size_t)(ot * 16 + ml) * 128;
                f32x4 acc = {0.f, 0.f, 0.f, 0.f};
#pragma unroll
                for (int k = 0; k < 4; k++)
                    acc = MFMA(a2[k], wfrag<WB>(wb + O_WM2, Wm2, wrow + k * 32 + q * 8), acc);
                // lane holds m[node=q*4+r][col=ot*16+ml]
                float s = 0.f;
#pragma unroll
                for (int r = 0; r < 4; r++)
                    s += w_all[q * 4 + r] * (acc[r] + bb2[ot]);
                wacc[ot] += s;
            }
        }
        __syncthreads();   // protect feaT before next tile's staging
    }

    // ---- cross-q reduction and f32 output ----
#pragma unroll
    for (int ot = 0; ot < 8; ot++) {
        wacc[ot] += __shfl_xor(wacc[ot], 16);
        wacc[ot] += __shfl_xor(wacc[ot], 32);
    }
    float inv = 1.f / (d_run + 1e-16f);
    if (q == 0) {
#pragma unroll
        for (int ot = 0; ot < 8; ot++)
            out[(size_t)c * 512 + h * 128 + ot * 16 + ml] = wacc[ot] * inv;
    }
}

template<bool WB>
__global__ __launch_bounds__(256) void fused_kernel(
    const float* fea, const float* cry,
    const float* Wm1, const float* bm1, const float* Wm2, const float* bm2,
    const float* Wa1, const float* ba1, const float* Wa2, const float* ba2,
    const __bf16* wb, const int* index, int N, float* out)
{
    fused_body<WB>(fea, cry, Wm1, bm1, Wm2, bm2, Wa1, ba1, Wa2, ba2,
                   wb, index, N, out);
}

// ---------------------------------------------------------------------------
extern "C" void kernel_launch(void* const* d_in, const int* in_sizes, int n_in,
                              void* d_out, int out_size, void* d_ws, size_t ws_size,
                              hipStream_t stream)
{
    const float* fea = (const float*)d_in[0];
    const float* cry = (const float*)d_in[1];
    const float* Wm1 = (const float*)d_in[2];
    const float* bm1 = (const float*)d_in[3];
    const float* Wm2 = (const float*)d_in[4];
    const float* bm2 = (const float*)d_in[5];
    const float* Wa1 = (const float*)d_in[6];
    const float* ba1 = (const float*)d_in[7];
    const float* Wa2 = (const float*)d_in[8];
    const float* ba2 = (const float*)d_in[9];
    const int* index = (const int*)d_in[10];

    const int N = in_sizes[0] / 128;      // 200000
    const int S = out_size / 512;         // 16384

    if (ws_size >= (size_t)W_ELEMS * 2) {
        __bf16* wb = (__bf16*)d_ws;
        prep_kernel<<<(W_ELEMS / 8 + 255) / 256, 256, 0, stream>>>(Wm1, Wm2, Wa1, Wa2, wb);
        fused_kernel<true><<<S, 256, 0, stream>>>(fea, cry, Wm1, bm1, Wm2, bm2,
                                                  Wa1, ba1, Wa2, ba2, wb, index, N,
                                                  (float*)d_out);
    } else {
        fused_kernel<false><<<S, 256, 0, stream>>>(fea, cry, Wm1, bm1, Wm2, bm2,
                                                   Wa1, ba1, Wa2, ba2, nullptr, index, N,
                                                   (float*)d_out);
    }
}